// Round 3
// baseline (1455.864 us; speedup 1.0000x reference)
//
#include <hip/hip_runtime.h>
#include <math.h>

#define BIG_NEG  (-1.0e6f)
#define NN   100
#define MD   128
#define KD   256
#define G4   512
#define MPAD 129   // (129*n + i) % 32 = (n+i)%32 -> 2-way alias = free

// ws layout:
//   floats [0, 32768)      : WembT [256][128] (W_emb transposed, fp32)
//   uints  [32768, 98304)  : WcatT2 [128][512] (bf16 pair per k-pair, gate-minor)
//   floats [98304, 98816)  : biasc = b_ih + b_hh
#define WS_WEMBT 0
#define WS_WCAT2 32768
#define WS_BIAS  98304

__device__ __forceinline__ unsigned short f2bf(float x) {
    unsigned u = __float_as_uint(x);
    unsigned r = (u + 0x7fffu + ((u >> 16) & 1u)) >> 16;   // RNE
    return (unsigned short)r;
}
__device__ __forceinline__ float sigm(float x) { return 1.0f / (1.0f + __expf(-x)); }

extern "C" __global__ void prep_kernel(const float* __restrict__ W_emb,
                                       const float* __restrict__ W_ih,
                                       const float* __restrict__ b_ih,
                                       const float* __restrict__ W_hh,
                                       const float* __restrict__ b_hh,
                                       float* __restrict__ ws) {
    int tid = blockIdx.x * blockDim.x + threadIdx.x;
    int nth = gridDim.x * blockDim.x;
    float*    WembT  = ws + WS_WEMBT;
    unsigned* WcatT2 = (unsigned*)ws + WS_WCAT2;
    float*    biasc  = ws + WS_BIAS;
    for (int i = tid; i < 256 * 128; i += nth) {
        int k = i >> 7, m = i & 127;
        WembT[i] = W_emb[m * 256 + k];
    }
    for (int i = tid; i < 128 * 512; i += nth) {
        int kp = i >> 9, g = i & 511;
        int k0 = kp * 2, k1 = kp * 2 + 1;
        float w0 = (k0 < 128) ? W_ih[g * 128 + k0] : W_hh[g * 128 + (k0 - 128)];
        float w1 = (k1 < 128) ? W_ih[g * 128 + k1] : W_hh[g * 128 + (k1 - 128)];
        WcatT2[i] = (unsigned)f2bf(w0) | ((unsigned)f2bf(w1) << 16);
    }
    for (int i = tid; i < 512; i += nth) biasc[i] = b_ih[i] + b_hh[i];
}

extern "C" __global__ __launch_bounds__(1024, 4)
void set2vec_main(const float* __restrict__ hidden,
                  const float* __restrict__ input,
                  const float* __restrict__ b_emb,
                  const unsigned char* __restrict__ mask_bytes,
                  const int* __restrict__ Tptr,
                  const float* __restrict__ ws,
                  float* __restrict__ out) {
    __shared__ float mem[2][NN][MPAD];       // 103200 B
    __shared__ float xcat2[2][KD];           // [lstm_in | h] per batch elem
    __shared__ float cbuf[2][MD];
    __shared__ float emask[2][NN];           // additive mask, constant over steps
    __shared__ int   mask_is_u8;
    __shared__ __align__(16) char scratch[32768];   // union: xtile | step partials

    float (*xtile)[KD] = (float (*)[KD])scratch;    // [32][256] embed staging
    float* gpart = (float*)scratch;                 // [kh:2][bb:2][512]  8192 B
    float* epart = (float*)(scratch + 8192);        // [bb:2][mq:4][100]  3200 B
    float* abuf  = (float*)(scratch + 11392);       // [bb:2][100]         800 B

    const int tid = threadIdx.x;
    const int b0  = blockIdx.x * 2;
    const float*    WembT  = ws + WS_WEMBT;
    const unsigned* WcatT2 = (const unsigned*)ws + WS_WCAT2;
    const float*    biasc  = ws + WS_BIAS;

    // sniff node_mask dtype (bool/u8 vs int32): int32 0/1 has zero bytes at i%4!=0
    if (tid == 0) {
        int nz = 0;
        for (int i = 0; i < 64; ++i)
            if ((i & 3) && mask_bytes[i]) nz = 1;
        mask_is_u8 = nz;
    }

    // ---- fused embed: mem = cat(hidden,input) @ W_emb^T + b_emb ----
    for (int t0 = 0; t0 < 2 * NN; t0 += 32) {
        int nrows = (2 * NN - t0 < 32) ? (2 * NN - t0) : 32;
        for (int h = 0; h < 2; ++h) {
            int idx = h * 1024 + tid;
            int rr = idx >> 6, q = idx & 63;
            if (rr < nrows) {
                int row = t0 + rr;
                int bb  = row >= NN;
                int n   = row - bb * NN;
                long base = ((long)(b0 + bb) * NN + n) << 7;
                const float* src = (q < 32) ? (hidden + base + (q << 2))
                                            : (input + base + ((q - 32) << 2));
                *(float4*)&xtile[rr][q << 2] = *(const float4*)src;
            }
        }
        __syncthreads();
        {
            int rr = tid >> 5, m0 = (tid & 31) << 2;
            if (rr < nrows) {
                float4 acc = *(const float4*)(b_emb + m0);
                const float* xr = xtile[rr];
                #pragma unroll 4
                for (int k = 0; k < KD; ++k) {
                    float  xv = xr[k];
                    float4 w  = *(const float4*)(WembT + k * MD + m0);
                    acc.x = fmaf(xv, w.x, acc.x); acc.y = fmaf(xv, w.y, acc.y);
                    acc.z = fmaf(xv, w.z, acc.z); acc.w = fmaf(xv, w.w, acc.w);
                }
                int row = t0 + rr, bb = row >= NN, n = row - bb * NN;
                float* dst = &mem[bb][n][m0];
                dst[0] = acc.x; dst[1] = acc.y; dst[2] = acc.z; dst[3] = acc.w;
            }
        }
        __syncthreads();
    }

    // ---- init LSTM state + mask table ----
    for (int i = tid; i < 2 * KD; i += 1024) ((float*)xcat2)[i] = 0.0f;
    if (tid < 256) ((float*)cbuf)[tid] = 0.0f;
    if (tid < 2 * NN) {
        int bb = tid >= NN, n = tid - bb * NN;
        long mrow = (long)(b0 + bb) * NN + n;
        int valid = mask_is_u8 ? (mask_bytes[mrow] != 0)
                               : (((const int*)mask_bytes)[mrow] != 0);
        emask[bb][n] = valid ? 0.0f : BIG_NEG;
    }
    __syncthreads();

    const int T = Tptr[0];   // works for i32 or i64-LE scalar

    // ---- per-thread phase constants ----
    const int g  = tid & 511, kh = tid >> 9;           // gates: (gate, k-half)
    const float2* xg0 = (const float2*)&xcat2[0][kh * 128];
    const float2* xg1 = (const float2*)&xcat2[1][kh * 128];
    const float bias0 = (kh == 0) ? biasc[g] : 0.0f;

    // gate weights are step-invariant: cache this thread's 64 bf16-pairs in VGPRs
    unsigned wreg[64];
    {
        const unsigned* Wg = WcatT2 + (kh * 64) * G4 + g;
        #pragma unroll
        for (int j = 0; j < 64; ++j) wreg[j] = Wg[j * G4];
    }

    const int e_act = tid < 800;                       // energies: (bb, mq, n)
    const int e_bb  = tid / 400;
    const int e_r   = tid - e_bb * 400;
    const int e_mq  = e_r / 100;
    const int e_n   = e_r - e_mq * 100;

    for (int step = 0; step < T; ++step) {
        // --- gates: one gate output per thread, half the K range, weights in regs ---
        {
            float a0 = bias0, a1 = bias0;
            #pragma unroll
            for (int j = 0; j < 64; ++j) {
                unsigned p   = wreg[j];
                float    wlo = __uint_as_float(p << 16);
                float    whi = __uint_as_float(p & 0xffff0000u);
                float2   v0  = xg0[j], v1 = xg1[j];
                a0 = fmaf(wlo, v0.x, a0); a0 = fmaf(whi, v0.y, a0);
                a1 = fmaf(wlo, v1.x, a1); a1 = fmaf(whi, v1.y, a1);
            }
            gpart[kh * 1024 + g]       = a0;   // [kh][0][g]
            gpart[kh * 1024 + 512 + g] = a1;   // [kh][1][g]
        }
        __syncthreads();
        // --- LSTM pointwise (i,f,g,o) + K-half combine ---
        if (tid < 256) {
            int bb = tid >> 7, m = tid & 127;
            const float* gp = gpart + bb * 512;
            float gi = gp[m]       + gp[1024 + m];
            float gf = gp[128 + m] + gp[1024 + 128 + m];
            float gg = gp[256 + m] + gp[1024 + 256 + m];
            float go = gp[384 + m] + gp[1024 + 384 + m];
            float c  = cbuf[bb][m];
            c = sigm(gf) * c + sigm(gi) * tanhf(gg);
            float q = sigm(go) * tanhf(c);
            cbuf[bb][m] = c;
            xcat2[bb][128 + m] = q;
        }
        __syncthreads();
        // --- energies partial: M split into quarters ---
        if (e_act) {
            const float* qv = &xcat2[e_bb][128 + e_mq * 32];
            const float* mr = &mem[e_bb][e_n][e_mq * 32];
            float e = 0.0f;
            #pragma unroll
            for (int i = 0; i < 32; ++i) e = fmaf(qv[i], mr[i], e);
            epart[tid] = e;              // layout [bb][mq][n]
        }
        __syncthreads();
        // --- softmax (combine partials + mask table) ---
        if (tid < 128) {
            int bb = tid >> 6, l = tid & 63;
            const float* ep = epart + bb * 400;
            float e0 = ep[l] + ep[100 + l] + ep[200 + l] + ep[300 + l] + emask[bb][l];
            float e1 = -INFINITY;
            if (l < 36) {
                int n1 = l + 64;
                e1 = ep[n1] + ep[100 + n1] + ep[200 + n1] + ep[300 + n1] + emask[bb][n1];
            }
            float mx = fmaxf(e0, e1);
            for (int off = 32; off; off >>= 1) mx = fmaxf(mx, __shfl_xor(mx, off, 64));
            float p0 = __expf(e0 - mx);
            float p1 = (l < 36) ? __expf(e1 - mx) : 0.0f;
            float s = p0 + p1;
            for (int off = 32; off; off >>= 1) s += __shfl_xor(s, off, 64);
            float inv = 1.0f / s;
            abuf[bb * 100 + l] = p0 * inv;
            if (l < 36) abuf[bb * 100 + l + 64] = p1 * inv;
        }
        __syncthreads();
        // --- read: full-N dot per (bb,m), 4 accumulator chains ---
        if (tid < 256) {
            int bb = tid >> 7, m = tid & 127;
            const float* ar = abuf + bb * 100;
            const float* mr = &mem[bb][0][m];
            float r0 = 0.0f, r1 = 0.0f, r2 = 0.0f, r3 = 0.0f;
            #pragma unroll
            for (int n = 0; n < 100; n += 4) {
                r0 = fmaf(ar[n],     mr[(n)     * MPAD], r0);
                r1 = fmaf(ar[n + 1], mr[(n + 1) * MPAD], r1);
                r2 = fmaf(ar[n + 2], mr[(n + 2) * MPAD], r2);
                r3 = fmaf(ar[n + 3], mr[(n + 3) * MPAD], r3);
            }
            xcat2[bb][m] = (r0 + r1) + (r2 + r3);   // lstm_in for next step
        }
        __syncthreads();
    }

    // ---- output: [q | read] ----
    if (tid < 512) {
        int bb = tid >> 8, j = tid & 255;
        float v = (j < 128) ? xcat2[bb][128 + j] : xcat2[bb][j - 128];
        out[((long)(b0 + bb) << 8) + j] = v;
    }
}

extern "C" void kernel_launch(void* const* d_in, const int* in_sizes, int n_in,
                              void* d_out, int out_size, void* d_ws, size_t ws_size,
                              hipStream_t stream) {
    const float* hidden = (const float*)d_in[0];
    const float* input  = (const float*)d_in[1];
    const float* W_emb  = (const float*)d_in[2];
    const float* b_emb  = (const float*)d_in[3];
    const float* W_ih   = (const float*)d_in[4];
    const float* b_ih   = (const float*)d_in[5];
    const float* W_hh   = (const float*)d_in[6];
    const float* b_hh   = (const float*)d_in[7];
    const unsigned char* mask = (const unsigned char*)d_in[8];
    const int*  Tptr    = (const int*)d_in[9];
    float* ws   = (float*)d_ws;
    float* outp = (float*)d_out;

    hipLaunchKernelGGL(prep_kernel, dim3(128), dim3(256), 0, stream,
                       W_emb, W_ih, b_ih, W_hh, b_hh, ws);
    hipLaunchKernelGGL(set2vec_main, dim3(1024), dim3(1024), 0, stream,
                       hidden, input, b_emb, mask, Tptr, ws, outp);
}

// Round 4
// 895.102 us; speedup vs baseline: 1.6265x; 1.6265x over previous
//
#include <hip/hip_runtime.h>
#include <hip/hip_fp16.h>
#include <math.h>

#define BIG_NEG  (-1.0e6f)
#define NN   100
#define MD   128
#define KD   256
#define G4   512
#define MP2  65   // mem m-pair row stride (65 % 32 == 1 -> 2-way alias = free)

// ws layout (float offsets):
//   [0, 32768)      : WembT fp32 [256][128]
//   [32768, 98304)  : WQ fp16-pair quads: uint[((kh*16+q)*512+g)*4+c], k = kh*128+q*8+2c
//   [98304, 98816)  : biasc = b_ih + b_hh
#define WS_WQ   32768
#define WS_BIAS 98304

__device__ __forceinline__ float sigm(float x) { return 1.0f / (1.0f + __expf(-x)); }

extern "C" __global__ void prep_kernel(const float* __restrict__ W_emb,
                                       const float* __restrict__ W_ih,
                                       const float* __restrict__ b_ih,
                                       const float* __restrict__ W_hh,
                                       const float* __restrict__ b_hh,
                                       float* __restrict__ ws) {
    int tid = blockIdx.x * blockDim.x + threadIdx.x;
    int nth = gridDim.x * blockDim.x;
    float*    WembT = ws;
    unsigned* WQ    = (unsigned*)ws + WS_WQ;
    float*    biasc = ws + WS_BIAS;
    for (int i = tid; i < 256 * 128; i += nth) {
        int k = i >> 7, m = i & 127;
        WembT[i] = W_emb[m * 256 + k];
    }
    for (int i = tid; i < 65536; i += nth) {
        int c = i & 3, g = (i >> 2) & 511, q = (i >> 11) & 15, kh = i >> 15;
        int k0 = kh * 128 + q * 8 + c * 2, k1 = k0 + 1;
        float w0 = (k0 < 128) ? W_ih[g * 128 + k0] : W_hh[g * 128 + (k0 - 128)];
        float w1 = (k1 < 128) ? W_ih[g * 128 + k1] : W_hh[g * 128 + (k1 - 128)];
        __half2 h = __floats2half2_rn(w0, w1);
        WQ[i] = *(unsigned*)&h;
    }
    for (int i = tid; i < 512; i += nth) biasc[i] = b_ih[i] + b_hh[i];
}

extern "C" __global__ __launch_bounds__(1024, 8)
void set2vec_main(const float* __restrict__ hidden,
                  const float* __restrict__ input,
                  const float* __restrict__ b_emb,
                  const unsigned char* __restrict__ mask_bytes,
                  const int* __restrict__ Tptr,
                  const float* __restrict__ ws,
                  float* __restrict__ out) {
    __shared__ __half2 mem2[2][NN][MP2];     // 52000 B, fp16-packed memory
    __shared__ float xcat2[2][KD];           // [lstm_in | h]
    __shared__ float cbuf[2][MD];
    __shared__ float emask[2][NN];
    __shared__ int   mask_is_u8;
    __shared__ __align__(16) char scratch[16384];   // xtile | step partials

    __half2 (*xtile)[128] = (__half2 (*)[128])scratch;   // [32][128] = 16384 B
    float* gpart = (float*)scratch;                      // [kh:2][bb:2][512] 8192 B
    float* epart = (float*)(scratch + 8192);             // [bb:2][mq:4][100] 3200 B
    float* abuf  = (float*)(scratch + 11392);            // [bb:2][100]        800 B

    const int tid = threadIdx.x;
    const int b0  = blockIdx.x * 2;
    const float* WembT = ws;
    const float* biasc = ws + WS_BIAS;

    if (tid == 0) {
        int nz = 0;
        for (int i = 0; i < 64; ++i)
            if ((i & 3) && mask_bytes[i]) nz = 1;
        mask_is_u8 = nz;
    }

    // ---- fused embed: mem2 = fp16(cat(hidden,input) @ W_emb^T + b_emb) ----
    for (int t0 = 0; t0 < 2 * NN; t0 += 32) {
        int nrows = (2 * NN - t0 < 32) ? (2 * NN - t0) : 32;
        for (int h = 0; h < 2; ++h) {
            int idx = h * 1024 + tid;
            int rr = idx >> 6, q = idx & 63;
            if (rr < nrows) {
                int row = t0 + rr, bb = row >= NN, n = row - bb * NN;
                long base = ((long)(b0 + bb) * NN + n) << 7;
                const float* src = (q < 32) ? (hidden + base + (q << 2))
                                            : (input + base + ((q - 32) << 2));
                float4 v = *(const float4*)src;
                xtile[rr][q * 2]     = __floats2half2_rn(v.x, v.y);
                xtile[rr][q * 2 + 1] = __floats2half2_rn(v.z, v.w);
            }
        }
        __syncthreads();
        {
            int rr = tid >> 5, m0 = (tid & 31) << 2;
            if (rr < nrows) {
                float4 acc = *(const float4*)(b_emb + m0);
                const __half2* xr = xtile[rr];
                #pragma unroll 2
                for (int kp = 0; kp < 128; ++kp) {
                    float2 xf = __half22float2(xr[kp]);
                    float4 w0 = *(const float4*)(WembT + (2 * kp) * MD + m0);
                    float4 w1 = *(const float4*)(WembT + (2 * kp + 1) * MD + m0);
                    acc.x = fmaf(xf.y, w1.x, fmaf(xf.x, w0.x, acc.x));
                    acc.y = fmaf(xf.y, w1.y, fmaf(xf.x, w0.y, acc.y));
                    acc.z = fmaf(xf.y, w1.z, fmaf(xf.x, w0.z, acc.z));
                    acc.w = fmaf(xf.y, w1.w, fmaf(xf.x, w0.w, acc.w));
                }
                int row = t0 + rr, bb = row >= NN, n = row - bb * NN;
                int mp = (tid & 31) * 2;
                mem2[bb][n][mp]     = __floats2half2_rn(acc.x, acc.y);
                mem2[bb][n][mp + 1] = __floats2half2_rn(acc.z, acc.w);
            }
        }
        __syncthreads();
    }

    // ---- init LSTM state + mask table ----
    for (int i = tid; i < 2 * KD; i += 1024) ((float*)xcat2)[i] = 0.0f;
    if (tid < 256) ((float*)cbuf)[tid] = 0.0f;
    if (tid < 2 * NN) {
        int bb = tid >= NN, n = tid - bb * NN;
        long mrow = (long)(b0 + bb) * NN + n;
        int valid = mask_is_u8 ? (mask_bytes[mrow] != 0)
                               : (((const int*)mask_bytes)[mrow] != 0);
        emask[bb][n] = valid ? 0.0f : BIG_NEG;
    }
    __syncthreads();

    const int T = Tptr[0];

    // ---- per-thread phase constants ----
    const int g = tid & 511, kh = tid >> 9;
    const uint4* Wg = (const uint4*)((const unsigned*)ws + WS_WQ) + (kh * 16) * G4 + g;
    const float2* xg0 = (const float2*)&xcat2[0][kh * 128];
    const float2* xg1 = (const float2*)&xcat2[1][kh * 128];
    const float bias0 = (kh == 0) ? biasc[g] : 0.0f;

    const int e_act = tid < 800;
    const int e_bb  = tid / 400;
    const int e_r   = tid - e_bb * 400;
    const int e_mq  = e_r / 100;
    const int e_n   = e_r - e_mq * 100;

    for (int step = 0; step < T; ++step) {
        // --- gates: one gate per thread, K-half, fp16 weight quads from L2 ---
        {
            float a0 = bias0, a1 = bias0;
            #pragma unroll 4
            for (int q = 0; q < 16; ++q) {
                uint4 wq = Wg[q * G4];
                float2 w0 = __half22float2(*(__half2*)&wq.x);
                float2 w1 = __half22float2(*(__half2*)&wq.y);
                float2 w2 = __half22float2(*(__half2*)&wq.z);
                float2 w3 = __half22float2(*(__half2*)&wq.w);
                float2 xa = xg0[q * 4], xb = xg0[q * 4 + 1], xc = xg0[q * 4 + 2], xd = xg0[q * 4 + 3];
                a0 = fmaf(w0.x, xa.x, a0); a0 = fmaf(w0.y, xa.y, a0);
                a0 = fmaf(w1.x, xb.x, a0); a0 = fmaf(w1.y, xb.y, a0);
                a0 = fmaf(w2.x, xc.x, a0); a0 = fmaf(w2.y, xc.y, a0);
                a0 = fmaf(w3.x, xd.x, a0); a0 = fmaf(w3.y, xd.y, a0);
                float2 ya = xg1[q * 4], yb = xg1[q * 4 + 1], yc = xg1[q * 4 + 2], yd = xg1[q * 4 + 3];
                a1 = fmaf(w0.x, ya.x, a1); a1 = fmaf(w0.y, ya.y, a1);
                a1 = fmaf(w1.x, yb.x, a1); a1 = fmaf(w1.y, yb.y, a1);
                a1 = fmaf(w2.x, yc.x, a1); a1 = fmaf(w2.y, yc.y, a1);
                a1 = fmaf(w3.x, yd.x, a1); a1 = fmaf(w3.y, yd.y, a1);
            }
            gpart[kh * 1024 + g]       = a0;
            gpart[kh * 1024 + 512 + g] = a1;
        }
        __syncthreads();
        // --- LSTM pointwise (i,f,g,o) + K-half combine ---
        if (tid < 256) {
            int bb = tid >> 7, m = tid & 127;
            const float* gp = gpart + bb * 512;
            float gi = gp[m]       + gp[1024 + m];
            float gf = gp[128 + m] + gp[1024 + 128 + m];
            float gg = gp[256 + m] + gp[1024 + 256 + m];
            float go = gp[384 + m] + gp[1024 + 384 + m];
            float c  = cbuf[bb][m];
            c = sigm(gf) * c + sigm(gi) * tanhf(gg);
            float qv = sigm(go) * tanhf(c);
            cbuf[bb][m] = c;
            xcat2[bb][128 + m] = qv;
        }
        __syncthreads();
        // --- energies partial: M in quarters, fp16 memory ---
        if (e_act) {
            const float2*  qv = (const float2*)&xcat2[e_bb][128 + e_mq * 32];
            const __half2* mr = &mem2[e_bb][e_n][e_mq * 16];
            float e = 0.0f;
            #pragma unroll
            for (int i = 0; i < 16; ++i) {
                float2 q2 = qv[i];
                float2 m2 = __half22float2(mr[i]);
                e = fmaf(q2.x, m2.x, e);
                e = fmaf(q2.y, m2.y, e);
            }
            epart[tid] = e;
        }
        __syncthreads();
        // --- softmax ---
        if (tid < 128) {
            int bb = tid >> 6, l = tid & 63;
            const float* ep = epart + bb * 400;
            float e0 = ep[l] + ep[100 + l] + ep[200 + l] + ep[300 + l] + emask[bb][l];
            float e1 = -INFINITY;
            if (l < 36) {
                int n1 = l + 64;
                e1 = ep[n1] + ep[100 + n1] + ep[200 + n1] + ep[300 + n1] + emask[bb][n1];
            }
            float mx = fmaxf(e0, e1);
            for (int off = 32; off; off >>= 1) mx = fmaxf(mx, __shfl_xor(mx, off, 64));
            float p0 = __expf(e0 - mx);
            float p1 = (l < 36) ? __expf(e1 - mx) : 0.0f;
            float s = p0 + p1;
            for (int off = 32; off; off >>= 1) s += __shfl_xor(s, off, 64);
            float inv = 1.0f / s;
            abuf[bb * 100 + l] = p0 * inv;
            if (l < 36) abuf[bb * 100 + l + 64] = p1 * inv;
        }
        __syncthreads();
        // --- read: full-N dot per (bb,m), 4 chains, fp16 memory ---
        if (tid < 256) {
            int bb = tid >> 7, m = tid & 127;
            int pi = m >> 1, hi = m & 1;
            const float* ar = abuf + bb * 100;
            const __half2* mrp = &mem2[bb][0][pi];
            float r0 = 0.0f, r1 = 0.0f, r2 = 0.0f, r3 = 0.0f;
            for (int n = 0; n < 100; n += 4) {
                __half2 h0 = mrp[n * MP2],       h1 = mrp[(n + 1) * MP2];
                __half2 h2 = mrp[(n + 2) * MP2], h3 = mrp[(n + 3) * MP2];
                float v0 = hi ? __high2float(h0) : __low2float(h0);
                float v1 = hi ? __high2float(h1) : __low2float(h1);
                float v2 = hi ? __high2float(h2) : __low2float(h2);
                float v3 = hi ? __high2float(h3) : __low2float(h3);
                r0 = fmaf(ar[n], v0, r0);     r1 = fmaf(ar[n + 1], v1, r1);
                r2 = fmaf(ar[n + 2], v2, r2); r3 = fmaf(ar[n + 3], v3, r3);
            }
            xcat2[bb][m] = (r0 + r1) + (r2 + r3);
        }
        __syncthreads();
    }

    // ---- output: [q | read] ----
    if (tid < 512) {
        int bb = tid >> 8, j = tid & 255;
        float v = (j < 128) ? xcat2[bb][128 + j] : xcat2[bb][j - 128];
        out[((long)(b0 + bb) << 8) + j] = v;
    }
}

extern "C" void kernel_launch(void* const* d_in, const int* in_sizes, int n_in,
                              void* d_out, int out_size, void* d_ws, size_t ws_size,
                              hipStream_t stream) {
    const float* hidden = (const float*)d_in[0];
    const float* input  = (const float*)d_in[1];
    const float* W_emb  = (const float*)d_in[2];
    const float* b_emb  = (const float*)d_in[3];
    const float* W_ih   = (const float*)d_in[4];
    const float* b_ih   = (const float*)d_in[5];
    const float* W_hh   = (const float*)d_in[6];
    const float* b_hh   = (const float*)d_in[7];
    const unsigned char* mask = (const unsigned char*)d_in[8];
    const int*  Tptr    = (const int*)d_in[9];
    float* ws   = (float*)d_ws;
    float* outp = (float*)d_out;

    hipLaunchKernelGGL(prep_kernel, dim3(128), dim3(256), 0, stream,
                       W_emb, W_ih, b_ih, W_hh, b_hh, ws);
    hipLaunchKernelGGL(set2vec_main, dim3(1024), dim3(1024), 0, stream,
                       hidden, input, b_emb, mask, Tptr, ws, outp);
}

// Round 5
// 257.779 us; speedup vs baseline: 5.6477x; 3.4724x over previous
//
#include <hip/hip_runtime.h>
#include <hip/hip_fp16.h>
#include <math.h>

#define BIG_NEG  (-1.0e6f)
#define NN   100
#define MD   128
#define KD   256
#define G4   512
#define MP2  65   // mem m-pair row stride (65 % 32 == 1 -> 2-way alias = free)

// ws layout:
//   halves [0, 32768)        : WembF fragment layout [kg:32][m:128][j:8], fp16
//   uints  [16384, 81920)    : WQ gate-weight quads (float-offset idx), as R4
//   floats [81920, 82432)    : biasc = b_ih + b_hh
#define WS_WQ_U   16384   // uint offset
#define WS_BIAS_F 81920   // float offset

typedef _Float16 f16x2 __attribute__((ext_vector_type(2)));
typedef _Float16 f16x8 __attribute__((ext_vector_type(8)));
typedef float    f32x4 __attribute__((ext_vector_type(4)));

__device__ __forceinline__ float sigm(float x) { return 1.0f / (1.0f + __expf(-x)); }

#if __has_builtin(__builtin_amdgcn_fdot2)
#define FDOT2(W, X, ACC) ACC = __builtin_amdgcn_fdot2((W), (X), (ACC), false)
#else
#define FDOT2(W, X, ACC) do { \
    f16x2 _w = (W), _x = (X); \
    ACC = fmaf((float)_w[0], (float)_x[0], ACC); \
    ACC = fmaf((float)_w[1], (float)_x[1], ACC); } while (0)
#endif

extern "C" __global__ void prep_kernel(const float* __restrict__ W_emb,
                                       const float* __restrict__ W_ih,
                                       const float* __restrict__ b_ih,
                                       const float* __restrict__ W_hh,
                                       const float* __restrict__ b_hh,
                                       float* __restrict__ ws) {
    int tid = blockIdx.x * blockDim.x + threadIdx.x;
    int nth = gridDim.x * blockDim.x;
    __half*   WF    = (__half*)ws;
    unsigned* WQ    = (unsigned*)ws + WS_WQ_U;
    float*    biasc = ws + WS_BIAS_F;
    // B-fragment layout for mfma_16x16x32_f16: lane needs W[k = kg*8+j][m]
    for (int i = tid; i < 32768; i += nth) {
        int kg = i >> 10, m = (i >> 3) & 127, j = i & 7;
        WF[i] = __float2half(W_emb[m * 256 + kg * 8 + j]);
    }
    for (int i = tid; i < 65536; i += nth) {
        int c = i & 3, g = (i >> 2) & 511, q = (i >> 11) & 15, kh = i >> 15;
        int k0 = kh * 128 + q * 8 + c * 2, k1 = k0 + 1;
        float w0 = (k0 < 128) ? W_ih[g * 128 + k0] : W_hh[g * 128 + (k0 - 128)];
        float w1 = (k1 < 128) ? W_ih[g * 128 + k1] : W_hh[g * 128 + (k1 - 128)];
        __half2 h = __floats2half2_rn(w0, w1);
        WQ[i] = *(unsigned*)&h;
    }
    for (int i = tid; i < 512; i += nth) biasc[i] = b_ih[i] + b_hh[i];
}

extern "C" __global__ __launch_bounds__(1024, 8)
void set2vec_main(const float* __restrict__ hidden,
                  const float* __restrict__ input,
                  const float* __restrict__ b_emb,
                  const unsigned char* __restrict__ mask_bytes,
                  const int* __restrict__ Tptr,
                  const float* __restrict__ ws,
                  float* __restrict__ out) {
    __shared__ __half2 mem2[2][NN][MP2];     // 52000 B fp16 memory
    __shared__ __half  xcath[2][KD];         // fp16 [lstm_in | h] (gates input)
    __shared__ float   xcat2[2][KD];         // fp32 [lstm_in | h] (energies/output)
    __shared__ float   cbuf[2][MD];
    __shared__ float   emask[2][NN];
    __shared__ int     mask_is_u8;
    __shared__ float   gpart[2][2][G4];      // [kh][bb][g] 8192 B
    __shared__ float   epart[2][4][NN];      // [bb][mq][n] 3200 B
    __shared__ float   abuf[2][NN];

    const int tid = threadIdx.x;
    const int b0  = blockIdx.x * 2;
    const __half* WF    = (const __half*)ws;
    const float*  biasc = ws + WS_BIAS_F;

    if (tid == 0) {
        int nz = 0;
        for (int i = 0; i < 64; ++i)
            if ((i & 3) && mask_bytes[i]) nz = 1;
        mask_is_u8 = nz;
    }

    // ---- fused embed via MFMA: mem = fp16(cat(hidden,input) @ W_emb^T + b_emb) ----
    {
        const int w    = tid >> 6;        // wave id = row-tile (0..12 active)
        const int lane = tid & 63;
        const int ln15 = lane & 15;
        const int lhi  = lane >> 4;
        if (w < 13) {
            // accumulators: 8 col-tiles of 16, named (no runtime indexing)
            float be0 = b_emb[0 * 16 + ln15], be1 = b_emb[1 * 16 + ln15];
            float be2 = b_emb[2 * 16 + ln15], be3 = b_emb[3 * 16 + ln15];
            float be4 = b_emb[4 * 16 + ln15], be5 = b_emb[5 * 16 + ln15];
            float be6 = b_emb[6 * 16 + ln15], be7 = b_emb[7 * 16 + ln15];
            f32x4 acc0 = {be0, be0, be0, be0}, acc1 = {be1, be1, be1, be1};
            f32x4 acc2 = {be2, be2, be2, be2}, acc3 = {be3, be3, be3, be3};
            f32x4 acc4 = {be4, be4, be4, be4}, acc5 = {be5, be5, be5, be5};
            f32x4 acc6 = {be6, be6, be6, be6}, acc7 = {be7, be7, be7, be7};

            const int rA     = w * 16 + ln15;            // A row (local)
            const int rAok   = rA < 200;
            const long gbase = ((long)(b0 * 100 + rA)) << 7;

            for (int mk = 0; mk < 8; ++mk) {
                // A fragment: x[rA][k0..k0+7] fp32 -> fp16
                f16x8 aF;
                if (rAok) {
                    int k0 = mk * 32 + lhi * 8;
                    const float* src = (k0 < 128) ? (hidden + gbase + k0)
                                                  : (input + gbase + (k0 - 128));
                    float4 v0 = *(const float4*)src;
                    float4 v1 = *(const float4*)(src + 4);
                    union { f16x8 v; f16x2 h[4]; } au;
                    au.h[0] = __builtin_bit_cast(f16x2, __builtin_amdgcn_cvt_pkrtz(v0.x, v0.y));
                    au.h[1] = __builtin_bit_cast(f16x2, __builtin_amdgcn_cvt_pkrtz(v0.z, v0.w));
                    au.h[2] = __builtin_bit_cast(f16x2, __builtin_amdgcn_cvt_pkrtz(v1.x, v1.y));
                    au.h[3] = __builtin_bit_cast(f16x2, __builtin_amdgcn_cvt_pkrtz(v1.z, v1.w));
                    aF = au.v;
                } else {
                    aF = (f16x8)(_Float16)0.0f;
                }
                const __half* wrow = WF + ((mk * 4 + lhi) * 128 + ln15) * 8;
#define EMB_CT(CT, ACC) { \
                union { uint4 u; f16x8 v; } bu; \
                bu.u = *(const uint4*)(wrow + (CT * 16) * 8); \
                ACC = __builtin_amdgcn_mfma_f32_16x16x32_f16(aF, bu.v, ACC, 0, 0, 0); }
                EMB_CT(0, acc0) EMB_CT(1, acc1) EMB_CT(2, acc2) EMB_CT(3, acc3)
                EMB_CT(4, acc4) EMB_CT(5, acc5) EMB_CT(6, acc6) EMB_CT(7, acc7)
#undef EMB_CT
            }
            // D layout: col = ln15 (+16*ct), row = lhi*4 + reg (+16*w)
            __half* memh = (__half*)mem2;
#define EMB_WR(CT, ACC) { \
            _Pragma("unroll") \
            for (int reg = 0; reg < 4; ++reg) { \
                int r = w * 16 + lhi * 4 + reg; \
                if (r < 200) { \
                    int bb = r >= 100, n = r - (r >= 100) * 100; \
                    memh[(bb * 100 + n) * (2 * MP2) + CT * 16 + ln15] = __float2half(ACC[reg]); \
                } } }
            EMB_WR(0, acc0) EMB_WR(1, acc1) EMB_WR(2, acc2) EMB_WR(3, acc3)
            EMB_WR(4, acc4) EMB_WR(5, acc5) EMB_WR(6, acc6) EMB_WR(7, acc7)
#undef EMB_WR
        }
    }

    // ---- init LSTM state + mask table ----
    for (int i = tid; i < 2 * KD; i += 1024) ((float*)xcat2)[i] = 0.0f;
    if (tid < 512) ((__half*)xcath)[tid] = __float2half(0.0f);
    if (tid < 256) ((float*)cbuf)[tid] = 0.0f;
    if (tid < 2 * NN) {
        int bb = tid >= NN, n = tid - bb * NN;
        long mrow = (long)(b0 + bb) * NN + n;
        int valid = mask_is_u8 ? (mask_bytes[mrow] != 0)
                               : (((const int*)mask_bytes)[mrow] != 0);
        emask[bb][n] = valid ? 0.0f : BIG_NEG;
    }
    __syncthreads();

    const int T = Tptr[0];

    // ---- per-thread phase constants ----
    const int g = tid & 511, kh = tid >> 9;
    const uint4* Wg = (const uint4*)((const unsigned*)ws + WS_WQ_U) + (kh * 16) * G4 + g;
    const f16x2* xg0 = (const f16x2*)&xcath[0][kh * 128];
    const f16x2* xg1 = (const f16x2*)&xcath[1][kh * 128];
    const float bias0 = (kh == 0) ? biasc[g] : 0.0f;

    const int e_act = tid < 800;
    const int e_bb  = tid / 400;
    const int e_r   = tid - e_bb * 400;
    const int e_mq  = e_r / 100;
    const int e_n   = e_r - e_mq * 100;

    for (int step = 0; step < T; ++step) {
        // --- gates: one gate per thread, K-half, fp16 dot2 ---
        {
            float a0 = bias0, a1 = bias0;
            #pragma unroll 4
            for (int q = 0; q < 16; ++q) {
                uint4 wq = Wg[q * G4];
                f16x2 w0 = __builtin_bit_cast(f16x2, wq.x);
                f16x2 w1 = __builtin_bit_cast(f16x2, wq.y);
                f16x2 w2 = __builtin_bit_cast(f16x2, wq.z);
                f16x2 w3 = __builtin_bit_cast(f16x2, wq.w);
                FDOT2(w0, xg0[q * 4 + 0], a0); FDOT2(w1, xg0[q * 4 + 1], a0);
                FDOT2(w2, xg0[q * 4 + 2], a0); FDOT2(w3, xg0[q * 4 + 3], a0);
                FDOT2(w0, xg1[q * 4 + 0], a1); FDOT2(w1, xg1[q * 4 + 1], a1);
                FDOT2(w2, xg1[q * 4 + 2], a1); FDOT2(w3, xg1[q * 4 + 3], a1);
            }
            gpart[kh][0][g] = a0;
            gpart[kh][1][g] = a1;
        }
        __syncthreads();
        // --- LSTM pointwise (i,f,g,o) + K-half combine ---
        if (tid < 256) {
            int bb = tid >> 7, m = tid & 127;
            float gi = gpart[0][bb][m]       + gpart[1][bb][m];
            float gf = gpart[0][bb][128 + m] + gpart[1][bb][128 + m];
            float gg = gpart[0][bb][256 + m] + gpart[1][bb][256 + m];
            float go = gpart[0][bb][384 + m] + gpart[1][bb][384 + m];
            float c  = cbuf[bb][m];
            c = sigm(gf) * c + sigm(gi) * tanhf(gg);
            float qv = sigm(go) * tanhf(c);
            cbuf[bb][m] = c;
            xcat2[bb][128 + m] = qv;
            xcath[bb][128 + m] = __float2half(qv);
        }
        __syncthreads();
        // --- energies partial: M in quarters, fp32 q x fp16 mem ---
        if (e_act) {
            const float2*  qv = (const float2*)&xcat2[e_bb][128 + e_mq * 32];
            const __half2* mr = &mem2[e_bb][e_n][e_mq * 16];
            float e = 0.0f;
            #pragma unroll
            for (int i = 0; i < 16; ++i) {
                float2 q2 = qv[i];
                float2 m2 = __half22float2(mr[i]);
                e = fmaf(q2.x, m2.x, e);
                e = fmaf(q2.y, m2.y, e);
            }
            epart[0][0][tid] = e;   // flat [bb][mq][n]
        }
        __syncthreads();
        // --- softmax ---
        if (tid < 128) {
            int bb = tid >> 6, l = tid & 63;
            const float* ep = &epart[bb][0][0];
            float e0 = ep[l] + ep[100 + l] + ep[200 + l] + ep[300 + l] + emask[bb][l];
            float e1 = -INFINITY;
            if (l < 36) {
                int n1 = l + 64;
                e1 = ep[n1] + ep[100 + n1] + ep[200 + n1] + ep[300 + n1] + emask[bb][n1];
            }
            float mx = fmaxf(e0, e1);
            for (int off = 32; off; off >>= 1) mx = fmaxf(mx, __shfl_xor(mx, off, 64));
            float p0 = __expf(e0 - mx);
            float p1 = (l < 36) ? __expf(e1 - mx) : 0.0f;
            float s = p0 + p1;
            for (int off = 32; off; off >>= 1) s += __shfl_xor(s, off, 64);
            float inv = 1.0f / s;
            abuf[bb][l] = p0 * inv;
            if (l < 36) abuf[bb][l + 64] = p1 * inv;
        }
        __syncthreads();
        // --- read: full-N dot per (bb,m), 4 chains, fp16 memory ---
        if (tid < 256) {
            int bb = tid >> 7, m = tid & 127;
            int pi = m >> 1, hi = m & 1;
            const float* ar = abuf[bb];
            const __half2* mrp = &mem2[bb][0][pi];
            float r0 = 0.0f, r1 = 0.0f, r2 = 0.0f, r3 = 0.0f;
            for (int n = 0; n < 100; n += 4) {
                __half2 h0 = mrp[n * MP2],       h1 = mrp[(n + 1) * MP2];
                __half2 h2 = mrp[(n + 2) * MP2], h3 = mrp[(n + 3) * MP2];
                float v0 = hi ? __high2float(h0) : __low2float(h0);
                float v1 = hi ? __high2float(h1) : __low2float(h1);
                float v2 = hi ? __high2float(h2) : __low2float(h2);
                float v3 = hi ? __high2float(h3) : __low2float(h3);
                r0 = fmaf(ar[n], v0, r0);     r1 = fmaf(ar[n + 1], v1, r1);
                r2 = fmaf(ar[n + 2], v2, r2); r3 = fmaf(ar[n + 3], v3, r3);
            }
            float res = (r0 + r1) + (r2 + r3);
            xcat2[bb][m] = res;
            xcath[bb][m] = __float2half(res);
        }
        __syncthreads();
    }

    // ---- output: [q | read] ----
    if (tid < 512) {
        int bb = tid >> 8, j = tid & 255;
        float v = (j < 128) ? xcat2[bb][128 + j] : xcat2[bb][j - 128];
        out[((long)(b0 + bb) << 8) + j] = v;
    }
}

extern "C" void kernel_launch(void* const* d_in, const int* in_sizes, int n_in,
                              void* d_out, int out_size, void* d_ws, size_t ws_size,
                              hipStream_t stream) {
    const float* hidden = (const float*)d_in[0];
    const float* input  = (const float*)d_in[1];
    const float* W_emb  = (const float*)d_in[2];
    const float* b_emb  = (const float*)d_in[3];
    const float* W_ih   = (const float*)d_in[4];
    const float* b_ih   = (const float*)d_in[5];
    const float* W_hh   = (const float*)d_in[6];
    const float* b_hh   = (const float*)d_in[7];
    const unsigned char* mask = (const unsigned char*)d_in[8];
    const int*  Tptr    = (const int*)d_in[9];
    float* ws   = (float*)d_ws;
    float* outp = (float*)d_out;

    hipLaunchKernelGGL(prep_kernel, dim3(128), dim3(256), 0, stream,
                       W_emb, W_ih, b_ih, W_hh, b_hh, ws);
    hipLaunchKernelGGL(set2vec_main, dim3(1024), dim3(1024), 0, stream,
                       hidden, input, b_emb, mask, Tptr, ws, outp);
}